// Round 4
// baseline (243.946 us; speedup 1.0000x reference)
//
#include <hip/hip_runtime.h>
#include <math.h>

#define B_  4
#define V_  256
#define C1_ 64
#define C2_ 32
#define H0_ 128
#define H2_ 256

typedef short bf16x8 __attribute__((ext_vector_type(8)));
typedef short bf16x4 __attribute__((ext_vector_type(4)));
typedef float f32x4  __attribute__((ext_vector_type(4)));

static __device__ __forceinline__ short f2bf(float f) {
    unsigned u = __float_as_uint(f);
    u += 0x7fffu + ((u >> 16) & 1u);          // RNE
    return (short)(u >> 16);
}

// ---------------------------------------------------------------------------
// Weight transpose+bf16 for MFMA fragments (device fn, folded into pre1_k).
// wsW layout (shorts): W1cT1[128*32] | W2T1[128*128] | W1cT2[128*32] | W2T2[128*128]
// ---------------------------------------------------------------------------
static __device__ void prep_dev(int idx,
    const float* __restrict__ W1c1, const float* __restrict__ W21,
    const float* __restrict__ W1c2, const float* __restrict__ W22,
    short* __restrict__ wsW)
{
    if (idx < 4096) {
        int n = idx >> 5, k = idx & 31;
        wsW[idx] = f2bf(W1c1[k * H0_ + n]);
    } else if (idx < 20480) {
        int t = idx - 4096; int n = t >> 7, k = t & 127;
        wsW[idx] = f2bf(W21[k * H0_ + n]);
    } else if (idx < 24576) {
        int t = idx - 20480; int n = t >> 5, k = t & 31;
        wsW[idx] = f2bf(W1c2[k * H0_ + n]);
    } else if (idx < 40960) {
        int t = idx - 24576; int n = t >> 7, k = t & 127;
        wsW[idx] = f2bf(W22[k * H0_ + n]);
    }
}

// ---------------------------------------------------------------------------
// Node hoist, 4 nodes/block: P = x@(W1a-W1b)+b1, Q = x@W1b.
// Waves 0-1 (tid<128) compute P, waves 2-3 compute Q; weight columns are
// loaded once and reused across the 4 nodes (4x less L2 traffic than R3).
// ---------------------------------------------------------------------------
template <int CIN>
static __device__ void node_pre4(int g,
    const float* __restrict__ x, const float* __restrict__ W1,
    const float* __restrict__ b1, float* __restrict__ P, float* __restrict__ Q)
{
    const int bi0 = g * 4;
    const int tid = threadIdx.x;
    const int n   = tid & 127;
    const bool isP = tid < 128;             // wave-uniform split

    __shared__ __align__(16) float s_x4[4][CIN];
    for (int idx = tid; idx < 4 * CIN; idx += 256)
        s_x4[idx / CIN][idx % CIN] = x[bi0 * CIN + idx];
    __syncthreads();

    float acc[4];
    float binit = isP ? b1[n] : 0.f;
    #pragma unroll
    for (int nd = 0; nd < 4; ++nd) acc[nd] = binit;

    for (int k = 0; k < CIN; k += 4) {
        float4 wv;
        if (isP) {
            wv.x = W1[(k + 0) * H0_ + n] - W1[(CIN + k + 0) * H0_ + n];
            wv.y = W1[(k + 1) * H0_ + n] - W1[(CIN + k + 1) * H0_ + n];
            wv.z = W1[(k + 2) * H0_ + n] - W1[(CIN + k + 2) * H0_ + n];
            wv.w = W1[(k + 3) * H0_ + n] - W1[(CIN + k + 3) * H0_ + n];
        } else {
            wv.x = W1[(CIN + k + 0) * H0_ + n];
            wv.y = W1[(CIN + k + 1) * H0_ + n];
            wv.z = W1[(CIN + k + 2) * H0_ + n];
            wv.w = W1[(CIN + k + 3) * H0_ + n];
        }
        #pragma unroll
        for (int nd = 0; nd < 4; ++nd) {
            float4 xv = *reinterpret_cast<const float4*>(&s_x4[nd][k]);
            acc[nd] = fmaf(xv.x, wv.x, acc[nd]);
            acc[nd] = fmaf(xv.y, wv.y, acc[nd]);
            acc[nd] = fmaf(xv.z, wv.z, acc[nd]);
            acc[nd] = fmaf(xv.w, wv.w, acc[nd]);
        }
    }
    float* dst = isP ? P : Q;
    #pragma unroll
    for (int nd = 0; nd < 4; ++nd)
        dst[(bi0 + nd) * H0_ + n] = acc[nd];
}

// pre1: blocks [0,256) do node_pre4 for conv1; [256,416) do weight prep.
__global__ __launch_bounds__(256) void pre1_k(
    const float* __restrict__ x, const float* __restrict__ W1,
    const float* __restrict__ b1, float* __restrict__ P, float* __restrict__ Q,
    const float* __restrict__ W1c1, const float* __restrict__ W21,
    const float* __restrict__ W1c2, const float* __restrict__ W22,
    short* __restrict__ wsW)
{
    if (blockIdx.x < 256) {
        node_pre4<C1_>(blockIdx.x, x, W1, b1, P, Q);
    } else {
        prep_dev((blockIdx.x - 256) * 256 + threadIdx.x, W1c1, W21, W1c2, W22, wsW);
    }
}

__global__ __launch_bounds__(256) void pre2_k(
    const float* __restrict__ x, const float* __restrict__ W1,
    const float* __restrict__ b1, float* __restrict__ P, float* __restrict__ Q)
{
    node_pre4<H0_>(blockIdx.x, x, W1, b1, P, Q);
}

// ---------------------------------------------------------------------------
// EdgeConvE main, transposed-GEMM1 MFMA version. Block = 2 nodes; 4 waves,
// each owns a 16-edge tile per 64-edge pass.
// GEMM1 (M=neurons, N=edges): A = W1c^T frags (global, L1-hot); B = e-frag
// (same load pattern as an A-frag); C-init = P[i]+Q[j] via one float4 per nt.
// Epilogue1: relu+bf16, ds_write_b64 into wave-private h1 rows (A-layout).
// GEMM2 (M=edges, N=neurons): B2 = W2^T persistent in registers.
// Pads duplicate real edges -> no masking needed anywhere (max-idempotent).
// ---------------------------------------------------------------------------
__global__ __launch_bounds__(256, 2) void conv_mfma_k(
    const int* __restrict__ adj, const float* __restrict__ e,
    const float* __restrict__ P, const float* __restrict__ Q,
    const short* __restrict__ W1cT, const short* __restrict__ W2T,
    const float* __restrict__ b2, float* __restrict__ out)
{
    const int g    = blockIdx.x;           // nodes 2g, 2g+1
    const int tid  = threadIdx.x;
    const int w    = tid >> 6;
    const int lane = tid & 63;
    const int l15  = lane & 15;
    const int quad = lane >> 4;
    const int row0 = w * 16;

    __shared__ int s_list[V_];
    __shared__ int s_cnt;
    __shared__ __align__(16) short s_h1[64][136];   // 272 B stride
    __shared__ __align__(16) float s_m[4][H0_];

    // persistent across both nodes: GEMM2 B-fragments + bias
    bf16x8 B2[8][4];
    #pragma unroll
    for (int nt = 0; nt < 8; ++nt)
        #pragma unroll
        for (int kk = 0; kk < 4; ++kk)
            B2[nt][kk] = *(const bf16x8*)(W2T + (nt * 16 + l15) * H0_ + kk * 32 + quad * 8);
    float bb[8];
    #pragma unroll
    for (int nt = 0; nt < 8; ++nt) bb[nt] = b2[nt * 16 + l15];

    for (int nd = 0; nd < 2; ++nd) {
        const int bi = g * 2 + nd;
        const int b  = bi >> 8;
        __syncthreads();                    // guard s_list/s_m reuse
        if (tid == 0) s_cnt = 0;
        __syncthreads();
        if (adj[bi * V_ + tid] > 0) { int p = atomicAdd(&s_cnt, 1); s_list[p] = tid; }
        __syncthreads();
        const int cnt = s_cnt;
        if (cnt == 0) { if (tid < H0_) out[bi * H0_ + tid] = 0.f; continue; }

        // P fragments for this node: row=neuron nt*16+quad*4..+3
        f32x4 Pp[8];
        #pragma unroll
        for (int nt = 0; nt < 8; ++nt)
            Pp[nt] = *(const f32x4*)(P + bi * H0_ + nt * 16 + quad * 4);

        float vmax[8];
        #pragma unroll
        for (int nt = 0; nt < 8; ++nt) vmax[nt] = -1e30f;

        for (int t0 = 0; t0 < cnt; t0 += 64) {
            int ta = t0 + row0 + l15; if (ta >= cnt) ta = cnt - 1;
            const int ja = s_list[ta];     // this lane's edge (col of GEMM1)

            // B-fragment from e (fp32 -> bf16): B[k=quad*8+j][n=l15]
            const float* er = e + (bi * V_ + ja) * C2_ + quad * 8;
            float4 e0 = *(const float4*)(er);
            float4 e1 = *(const float4*)(er + 4);
            bf16x8 Bf;
            Bf[0] = f2bf(e0.x); Bf[1] = f2bf(e0.y); Bf[2] = f2bf(e0.z); Bf[3] = f2bf(e0.w);
            Bf[4] = f2bf(e1.x); Bf[5] = f2bf(e1.y); Bf[6] = f2bf(e1.z); Bf[7] = f2bf(e1.w);

            // GEMM1 with C-init = P[i] + Q[j]; epilogue: relu+bf16 -> LDS b64
            const float* Qr = Q + (b * V_ + ja) * H0_;
            #pragma unroll
            for (int nt = 0; nt < 8; ++nt) {
                bf16x8 A1 = *(const bf16x8*)(W1cT + (nt * 16 + l15) * C2_ + quad * 8);
                f32x4 c4 = Pp[nt] + *(const f32x4*)(Qr + nt * 16 + quad * 4);
                f32x4 acc = __builtin_amdgcn_mfma_f32_16x16x32_bf16(A1, Bf, c4, 0, 0, 0);
                bf16x4 hv;
                hv[0] = f2bf(fmaxf(acc[0], 0.f));
                hv[1] = f2bf(fmaxf(acc[1], 0.f));
                hv[2] = f2bf(fmaxf(acc[2], 0.f));
                hv[3] = f2bf(fmaxf(acc[3], 0.f));
                *(bf16x4*)(&s_h1[row0 + l15][nt * 16 + quad * 4]) = hv;
            }

            // GEMM2: h1 @ W2 (wave-private rows, B2 in registers)
            f32x4 acc2[8];
            #pragma unroll
            for (int nt = 0; nt < 8; ++nt) { f32x4 z = {0.f,0.f,0.f,0.f}; acc2[nt] = z; }
            #pragma unroll
            for (int kk = 0; kk < 4; ++kk) {
                bf16x8 A2 = *(const bf16x8*)(&s_h1[row0 + l15][kk * 32 + quad * 8]);
                #pragma unroll
                for (int nt = 0; nt < 8; ++nt)
                    acc2[nt] = __builtin_amdgcn_mfma_f32_16x16x32_bf16(A2, B2[nt][kk], acc2[nt], 0, 0, 0);
            }
            // column max over this wave's 16 edge rows (pads = dup real edges)
            #pragma unroll
            for (int nt = 0; nt < 8; ++nt) {
                float m = fmaxf(fmaxf(acc2[nt][0], acc2[nt][1]),
                                fmaxf(acc2[nt][2], acc2[nt][3]));
                vmax[nt] = fmaxf(vmax[nt], m);
            }
        }

        // cross-quad (edge rows) max, bias+relu, then cross-wave via LDS
        #pragma unroll
        for (int nt = 0; nt < 8; ++nt) {
            float p = vmax[nt];
            p = fmaxf(p, __shfl_xor(p, 16, 64));
            p = fmaxf(p, __shfl_xor(p, 32, 64));
            if (quad == 0) s_m[w][nt * 16 + l15] = fmaxf(p + bb[nt], 0.f);
        }
        __syncthreads();
        if (tid < H0_) {
            float m = fmaxf(fmaxf(s_m[0][tid], s_m[1][tid]),
                            fmaxf(s_m[2][tid], s_m[3][tid]));
            out[bi * H0_ + tid] = m;
        }
    }
}

// ---------------------------------------------------------------------------
// Pair hoist, 4 nodes/block: Ai = x2@W3[H0:]+b3, Aj = x2@W3[:H0].
// W3 columns loaded once, reused across 4 nodes.
// ---------------------------------------------------------------------------
__global__ __launch_bounds__(256) void pair_pre4_k(
    const float* __restrict__ x2, const float* __restrict__ W3,
    const float* __restrict__ b3, float* __restrict__ Ai, float* __restrict__ Aj)
{
    const int bi0 = blockIdx.x * 4;
    const int n   = threadIdx.x;             // neuron 0..255

    __shared__ __align__(16) float s_x4[4][H0_];
    for (int idx = n; idx < 4 * H0_; idx += 256)
        s_x4[idx >> 7][idx & 127] = x2[bi0 * H0_ + idx];
    __syncthreads();

    float aI[4], aJ[4];
    const float bv = b3[n];
    #pragma unroll
    for (int nd = 0; nd < 4; ++nd) { aI[nd] = bv; aJ[nd] = 0.f; }

    for (int k = 0; k < H0_; k += 4) {
        float4 wj, wi;
        wj.x = W3[(k + 0) * H2_ + n];        wi.x = W3[(H0_ + k + 0) * H2_ + n];
        wj.y = W3[(k + 1) * H2_ + n];        wi.y = W3[(H0_ + k + 1) * H2_ + n];
        wj.z = W3[(k + 2) * H2_ + n];        wi.z = W3[(H0_ + k + 2) * H2_ + n];
        wj.w = W3[(k + 3) * H2_ + n];        wi.w = W3[(H0_ + k + 3) * H2_ + n];
        #pragma unroll
        for (int nd = 0; nd < 4; ++nd) {
            float4 xv = *reinterpret_cast<const float4*>(&s_x4[nd][k]);
            aJ[nd] = fmaf(xv.x, wj.x, aJ[nd]);  aI[nd] = fmaf(xv.x, wi.x, aI[nd]);
            aJ[nd] = fmaf(xv.y, wj.y, aJ[nd]);  aI[nd] = fmaf(xv.y, wi.y, aI[nd]);
            aJ[nd] = fmaf(xv.z, wj.z, aJ[nd]);  aI[nd] = fmaf(xv.z, wi.z, aI[nd]);
            aJ[nd] = fmaf(xv.w, wj.w, aJ[nd]);  aI[nd] = fmaf(xv.w, wi.w, aI[nd]);
        }
    }
    #pragma unroll
    for (int nd = 0; nd < 4; ++nd) {
        Ai[(bi0 + nd) * H2_ + n] = aI[nd];
        Aj[(bi0 + nd) * H2_ + n] = aJ[nd];
    }
}

// ---------------------------------------------------------------------------
// Pair output (unchanged from R3): block = 4 i's, wave = one i, lane=(jj,c).
// ---------------------------------------------------------------------------
__global__ __launch_bounds__(256) void pair_out_k(
    const float* __restrict__ Ai, const float* __restrict__ Aj,
    const float* __restrict__ Wo, const float* __restrict__ bo,
    float* __restrict__ out)
{
    const int blk  = blockIdx.x;
    const int b    = blk >> 6;
    const int i    = ((blk & 63) << 2) + (threadIdx.x >> 6);
    const int lane = threadIdx.x & 63;
    const int jj   = lane >> 4;
    const int c    = lane & 15;

    const float* ai = Ai + (b * V_ + i) * H2_ + c * 16;
    float4 a0 = *(const float4*)(ai);
    float4 a1 = *(const float4*)(ai + 4);
    float4 a2 = *(const float4*)(ai + 8);
    float4 a3 = *(const float4*)(ai + 12);
    const float* wo = Wo + c * 16;
    float4 w0 = *(const float4*)(wo);
    float4 w1 = *(const float4*)(wo + 4);
    float4 w2 = *(const float4*)(wo + 8);
    float4 w3 = *(const float4*)(wo + 12);
    const float bo0 = bo[0];

    for (int j0 = 0; j0 < V_; j0 += 4) {
        const int j = j0 + jj;
        const float* aj = Aj + (b * V_ + j) * H2_ + c * 16;
        float4 q0 = *(const float4*)(aj);
        float4 q1 = *(const float4*)(aj + 4);
        float4 q2 = *(const float4*)(aj + 8);
        float4 q3 = *(const float4*)(aj + 12);
        float p;
        p = fmaxf(a0.x + q0.x, 0.f) * w0.x;
        p = fmaf(fmaxf(a0.y + q0.y, 0.f), w0.y, p);
        p = fmaf(fmaxf(a0.z + q0.z, 0.f), w0.z, p);
        p = fmaf(fmaxf(a0.w + q0.w, 0.f), w0.w, p);
        p = fmaf(fmaxf(a1.x + q1.x, 0.f), w1.x, p);
        p = fmaf(fmaxf(a1.y + q1.y, 0.f), w1.y, p);
        p = fmaf(fmaxf(a1.z + q1.z, 0.f), w1.z, p);
        p = fmaf(fmaxf(a1.w + q1.w, 0.f), w1.w, p);
        p = fmaf(fmaxf(a2.x + q2.x, 0.f), w2.x, p);
        p = fmaf(fmaxf(a2.y + q2.y, 0.f), w2.y, p);
        p = fmaf(fmaxf(a2.z + q2.z, 0.f), w2.z, p);
        p = fmaf(fmaxf(a2.w + q2.w, 0.f), w2.w, p);
        p = fmaf(fmaxf(a3.x + q3.x, 0.f), w3.x, p);
        p = fmaf(fmaxf(a3.y + q3.y, 0.f), w3.y, p);
        p = fmaf(fmaxf(a3.z + q3.z, 0.f), w3.z, p);
        p = fmaf(fmaxf(a3.w + q3.w, 0.f), w3.w, p);
        #pragma unroll
        for (int off = 1; off < 16; off <<= 1)
            p += __shfl_xor(p, off, 64);
        if (c == 0)
            out[(b * V_ + i) * V_ + j] = 1.f / (1.f + __builtin_expf(-(p + bo0)));
    }
}

// ---------------------------------------------------------------------------
extern "C" void kernel_launch(void* const* d_in, const int* in_sizes, int n_in,
                              void* d_out, int out_size, void* d_ws, size_t ws_size,
                              hipStream_t stream) {
    const int*   adj   = (const int*)  d_in[0];
    const float* xf    = (const float*)d_in[1];
    const float* ea    = (const float*)d_in[2];
    const float* ec1W1 = (const float*)d_in[3];
    const float* ec1b1 = (const float*)d_in[4];
    const float* ec1W2 = (const float*)d_in[5];
    const float* ec1b2 = (const float*)d_in[6];
    const float* ec2W1 = (const float*)d_in[7];
    const float* ec2b1 = (const float*)d_in[8];
    const float* ec2W2 = (const float*)d_in[9];
    const float* ec2b2 = (const float*)d_in[10];
    const float* h3W   = (const float*)d_in[11];
    const float* h3b   = (const float*)d_in[12];
    const float* oW    = (const float*)d_in[13];
    const float* ob    = (const float*)d_in[14];
    float* out = (float*)d_out;

    const int NV = B_ * V_;                    // 1024 nodes
    float* x1 = (float*)d_ws;                  // NV*H0
    float* x2 = x1 + NV * H0_;                 // NV*H0
    float* R  = x2 + NV * H0_;                 // reuse region
    float* P  = R;                             // NV*H0
    float* Q  = R + NV * H0_;                  // NV*H0
    float* Ai = R;                             // NV*H2 (P/Q dead by then)
    float* Aj = R + NV * H2_;                  // NV*H2
    short* wsW = (short*)(R + 2 * NV * H2_);   // 40960 bf16 weights
    short* W1cT1 = wsW;
    short* W2T1  = wsW + 4096;
    short* W1cT2 = wsW + 20480;
    short* W2T2  = wsW + 24576;

    // conv1 hoist + weight prep (fused)
    pre1_k<<<416, 256, 0, stream>>>(xf, ec1W1, ec1b1, P, Q,
                                    ec1W1 + 2 * C1_ * H0_, ec1W2,
                                    ec2W1 + 2 * H0_ * H0_, ec2W2, wsW);
    conv_mfma_k<<<NV / 2, 256, 0, stream>>>(adj, ea, P, Q, W1cT1, W2T1, ec1b2, x1);
    pre2_k<<<256, 256, 0, stream>>>(x1, ec2W1, ec2b1, P, Q);
    conv_mfma_k<<<NV / 2, 256, 0, stream>>>(adj, ea, P, Q, W1cT2, W2T2, ec2b2, x2);
    pair_pre4_k<<<256, 256, 0, stream>>>(x2, h3W, h3b, Ai, Aj);
    pair_out_k<<<B_ * V_ / 4, 256, 0, stream>>>(Ai, Aj, oW, ob, out);
}